// Round 9
// baseline (2471.370 us; speedup 1.0000x reference)
//
#include <hip/hip_runtime.h>
#include <hip/hip_fp16.h>

typedef _Float16 h2 __attribute__((ext_vector_type(2)));
typedef _Float16 half8 __attribute__((ext_vector_type(8)));
typedef float f32x4 __attribute__((ext_vector_type(4)));
typedef unsigned int u32;

#define B_ 256
#define T_ 512
#define F_ 256
#define H_ 512

__device__ __forceinline__ u32 packh2(float a, float b) {
    h2 v; v[0] = (_Float16)a; v[1] = (_Float16)b;
    return __builtin_bit_cast(u32, v);
}

__device__ __forceinline__ float fast_tanh(float x) {
    float t = fminf(fmaxf(x, -12.f), 12.f);
    float s = __expf(2.f * t);
    return 1.f - 2.f * __builtin_amdgcn_rcpf(s + 1.f);
}

// Prepack regions (flat tid over 384*512 = 196608):
//   [0, 65536)        : Bg — MFMA-fragment-ready Wx (xp GEMM B):
//                       J(ks,nt,l,j) = ((ks*32+nt)*64+l)*4+j
//                       f = ks*32 + (l>>4)*8 + 2j, n = nt*16 + (l&15)
//   [65536, 196608)   : Bh — MFMA-fragment-ready Wh (RNN B), per RNN thread t
//                       64 uint4 chunks c = nt*16+ks, word y:
//                       k0 = 32ks + 8*((t&63)>>4) + 2y, n = 64*(t>>6) + 16nt + (t&15)
//                       value = pack(Wh[k0][n], Wh[k0+1][n])
__global__ __launch_bounds__(512) void prepack_kernel(const float* __restrict__ Wx,
                                                      const float* __restrict__ Wh,
                                                      u32* __restrict__ Bg,
                                                      u32* __restrict__ Bh) {
    int id = blockIdx.x * 512 + threadIdx.x;
    if (id < 65536) {
        int j = id & 3, l = (id >> 2) & 63, nt = (id >> 8) & 31, ks = id >> 13;
        int f = ks * 32 + (l >> 4) * 8 + 2 * j;
        int n = nt * 16 + (l & 15);
        Bg[id] = packh2(Wx[f * H_ + n], Wx[(f + 1) * H_ + n]);
    } else {
        int k = id - 65536;                 // 0..131071
        int y = k & 3, t = (k >> 2) & 511, c = k >> 11;
        int nt = c >> 4, ks = c & 15;
        int w = t >> 6, lh = (t >> 4) & 3, ln = t & 15;
        int k0 = 32 * ks + 8 * lh + 2 * y;
        int n  = 64 * w + 16 * nt + ln;
        Bh[k] = packh2(Wh[k0 * H_ + n], Wh[(k0 + 1) * H_ + n]);
    }
}

__device__ __forceinline__ void gload16(const uint4* g, uint4* l) {
    __builtin_amdgcn_global_load_lds((const __attribute__((address_space(1))) u32*)g,
                                     (__attribute__((address_space(3))) u32*)l, 16, 0, 0);
}

// MFMA GEMM: xp = x @ Wx + b, output stored in RNN-consumable layout:
//   f16 addr = g*4194304 + (ts*4 + m&3)*2048 + tid*4 + nt   (tid = RNN thread, nt = 0..3)
//   i.e. uint2 index = g*1048576 + (ts*4 + mml)*512 + tid, 4 f16 (nt) per uint2.
__global__ __launch_bounds__(512) void xp_mfma_kernel(const float* __restrict__ x,
                                                      const uint4* __restrict__ Bg,
                                                      const float* __restrict__ b,
                                                      uint2* __restrict__ xp2) {
    extern __shared__ u32 smem[];
    uint4* alds  = (uint4*)smem;      // 4096 uint4 = 64 KB
    uint4* bbuf0 = alds + 4096;       // 2048 uint4 = 32 KB
    uint4* bbuf1 = bbuf0 + 2048;      // 2048 uint4 = 32 KB

    const int tid  = threadIdx.x;
    const int lane = tid & 63;
    const int w    = tid >> 6;
    const int cg   = w & 1;
    const int rg   = w >> 1;
    const long row0 = (long)blockIdx.x * 128;

#pragma unroll
    for (int it = 0; it < 4; ++it)
        gload16(Bg + it * 512 + tid, bbuf0 + it * 512 + tid);

    const float4* x4 = (const float4*)(x + row0 * F_);
#pragma unroll
    for (int it = 0; it < 8; ++it) {
        int s  = it * 512 + tid;
        int rt = s >> 9, ks = (s >> 6) & 7, l = s & 63;
        int row = rt * 16 + (l & 15);
        int f0  = ks * 32 + (l >> 4) * 8;
        float4 a = x4[row * 64 + (f0 >> 2)];
        float4 c = x4[row * 64 + (f0 >> 2) + 1];
        uint4 pv;
        pv.x = packh2(a.x, a.y); pv.y = packh2(a.z, a.w);
        pv.z = packh2(c.x, c.y); pv.w = packh2(c.z, c.w);
        alds[s] = pv;
    }

    float bias[16];
#pragma unroll
    for (int nt = 0; nt < 16; ++nt) bias[nt] = b[cg * 256 + nt * 16 + (lane & 15)];

    f32x4 acc0[16], acc1[16];
#pragma unroll
    for (int nt = 0; nt < 16; ++nt) {
        acc0[nt] = (f32x4){0.f, 0.f, 0.f, 0.f};
        acc1[nt] = (f32x4){0.f, 0.f, 0.f, 0.f};
    }

    __syncthreads();

#pragma unroll
    for (int ks = 0; ks < 8; ++ks) {
        const uint4* blr = (ks & 1) ? bbuf1 : bbuf0;
        if (ks < 7) {
            uint4* bw = (ks & 1) ? bbuf0 : bbuf1;
            const uint4* gs = Bg + (ks + 1) * 2048;
#pragma unroll
            for (int it = 0; it < 4; ++it)
                gload16(gs + it * 512 + tid, bw + it * 512 + tid);
        }
        uint4 af0 = alds[((rg * 2 + 0) * 8 + ks) * 64 + lane];
        uint4 af1 = alds[((rg * 2 + 1) * 8 + ks) * 64 + lane];
        half8 a0 = __builtin_bit_cast(half8, af0);
        half8 a1 = __builtin_bit_cast(half8, af1);
#pragma unroll
        for (int nt = 0; nt < 16; ++nt) {
            uint4 bf = blr[(cg * 16 + nt) * 64 + lane];
            half8 bb = __builtin_bit_cast(half8, bf);
            acc0[nt] = __builtin_amdgcn_mfma_f32_16x16x32_f16(a0, bb, acc0[nt], 0, 0, 0);
            acc1[nt] = __builtin_amdgcn_mfma_f32_16x16x32_f16(a1, bb, acc1[nt], 0, 0, 0);
        }
        __syncthreads();
    }

    // ---- epilogue: D lane map col = lane&15, row = (lane>>4)*4 + r ----
    // GEMM rows = b*512 + ts (one sample b per 128-row block). Store into RNN layout.
    const int m0  = (lane >> 4) * 4;
    const int bs  = (int)(row0 >> 9);          // sample index (const per block)
    const int g   = bs >> 4, mm = bs & 15;
    const int mml = mm & 3, mmh = (mm >> 2) << 4;
    const size_t gb2 = (size_t)g * 1048576;    // uint2 per g
#pragma unroll
    for (int mt = 0; mt < 2; ++mt) {
        long rb = row0 + (rg * 2 + mt) * 16 + m0;
        const f32x4* accp = mt ? acc1 : acc0;
#pragma unroll
        for (int q = 0; q < 4; ++q) {
            int rtid = (cg * 4 + q) * 64 + mmh + (lane & 15);
#pragma unroll
            for (int r = 0; r < 4; ++r) {
                int tsv = (int)((rb + r) & 511);
                uint2 pv;
                pv.x = packh2(accp[4 * q + 0][r] + bias[4 * q + 0],
                              accp[4 * q + 1][r] + bias[4 * q + 1]);
                pv.y = packh2(accp[4 * q + 2][r] + bias[4 * q + 2],
                              accp[4 * q + 3][r] + bias[4 * q + 3]);
                xp2[gb2 + (size_t)(tsv * 4 + mml) * 512 + rtid] = pv;
            }
        }
    }
}

// MFMA RNN: 16 blocks x 512 thr (8 waves). Block g owns samples [16g,16g+16).
// Per step: D[16,512] = h @ Wh via 512 x mfma_16x16x32_f16 (64/wave; wave w owns
// n-cols [64w,64w+64) = 4 n-tiles, full K). Wh resident as 256 B-frag regs/thread
// (MFMA-only -> AGPR-friendly). h exchanged per step through a 16KB double-buffered
// LDS tile, slot-swizzled (slot ^= m) -> conflict-free b128 A-reads, ~2-way writes.
// One barrier/step, no cross-wave f32 reduction, no readlanes.
__global__ __launch_bounds__(512) __attribute__((amdgpu_waves_per_eu(2, 2)))
void rnn_mfma_kernel(const uint2* __restrict__ xp2,
                     const uint4* __restrict__ Bh4,
                     const float* __restrict__ Wfc,
                     const float* __restrict__ bfc,
                     float* __restrict__ out) {
    extern __shared__ u32 lds[];
    uint4* hb4 = (uint4*)lds;            // 2 x 1024 uint4 = 32 KB (h double buffer)
    __half* hh = (__half*)lds;
    float* pex = (float*)(lds + 8192);   // 8 KB epilogue exchange

    const int t  = threadIdx.x;
    const int w  = t >> 6;
    const int l  = t & 63;
    const int ln = l & 15;
    const int kg = l >> 4;
    const int g  = blockIdx.x;

    // resident Wh B-fragments: chunk c = nt*16+ks
    uint4 bfr[64];
#pragma unroll
    for (int c = 0; c < 64; ++c) bfr[c] = Bh4[c * 512 + t];

    float wfc[4];
#pragma unroll
    for (int nt = 0; nt < 4; ++nt) wfc[nt] = Wfc[64 * w + 16 * nt + ln];

    // zero h buffer 0 (h0 = 0)
    uint4 z4; z4.x = 0; z4.y = 0; z4.z = 0; z4.w = 0;
    hb4[t * 2] = z4; hb4[t * 2 + 1] = z4;
    __syncthreads();

    const uint2* xg = xp2 + (size_t)g * 1048576;
    const int abase0 = ln * 64;          // A-row base (uint4 units) within buffer

    int cur = 0;
    for (int ts = 0; ts < T_; ++ts) {
        // xp loads: 4 x 8B coalesced (r = 0..3), each holds nt 0..3 for this thread
        uint2 xq0 = xg[(size_t)(ts * 4 + 0) * 512 + t];
        uint2 xq1 = xg[(size_t)(ts * 4 + 1) * 512 + t];
        uint2 xq2 = xg[(size_t)(ts * 4 + 2) * 512 + t];
        uint2 xq3 = xg[(size_t)(ts * 4 + 3) * 512 + t];

        const int ab = cur * 1024 + abase0;
        f32x4 acc0 = {0.f, 0.f, 0.f, 0.f}, acc1 = {0.f, 0.f, 0.f, 0.f};
        f32x4 acc2 = {0.f, 0.f, 0.f, 0.f}, acc3 = {0.f, 0.f, 0.f, 0.f};
        // A-frag: lane reads h[m=ln][k = 32ks+8kg .. +8]; phys slot = (4ks+kg)^ln
        uint4 a_cur = hb4[ab + (kg ^ ln)];
#pragma unroll
        for (int ks = 0; ks < 16; ++ks) {
            uint4 a_nxt = a_cur;
            if (ks < 15) a_nxt = hb4[ab + ((4 * (ks + 1) + kg) ^ ln)];
            half8 a8 = __builtin_bit_cast(half8, a_cur);
            acc0 = __builtin_amdgcn_mfma_f32_16x16x32_f16(a8, __builtin_bit_cast(half8, bfr[0 * 16 + ks]), acc0, 0, 0, 0);
            acc1 = __builtin_amdgcn_mfma_f32_16x16x32_f16(a8, __builtin_bit_cast(half8, bfr[1 * 16 + ks]), acc1, 0, 0, 0);
            acc2 = __builtin_amdgcn_mfma_f32_16x16x32_f16(a8, __builtin_bit_cast(half8, bfr[2 * 16 + ks]), acc2, 0, 0, 0);
            acc3 = __builtin_amdgcn_mfma_f32_16x16x32_f16(a8, __builtin_bit_cast(half8, bfr[3 * 16 + ks]), acc3, 0, 0, 0);
            a_cur = a_nxt;
        }
        // tail: h = tanh(D + xp); write h[mm = 4kg+r][n] f16 to buffer cur^1 (swizzled)
        const int wb = (cur ^ 1) * 8192;
        h2 xh0 = __builtin_bit_cast(h2, xq0.x), xh1 = __builtin_bit_cast(h2, xq0.y);
        h2 xh2 = __builtin_bit_cast(h2, xq1.x), xh3 = __builtin_bit_cast(h2, xq1.y);
        h2 xh4 = __builtin_bit_cast(h2, xq2.x), xh5 = __builtin_bit_cast(h2, xq2.y);
        h2 xh6 = __builtin_bit_cast(h2, xq3.x), xh7 = __builtin_bit_cast(h2, xq3.y);
#pragma unroll
        for (int nt = 0; nt < 4; ++nt) {
            const int n = 64 * w + 16 * nt + ln;
#pragma unroll
            for (int r = 0; r < 4; ++r) {
                float dv = (nt == 0 ? acc0[r] : nt == 1 ? acc1[r] : nt == 2 ? acc2[r] : acc3[r]);
                // xp value for (nt, r): uint2 r, f16 slot nt
                h2 xp_pair = (r == 0 ? (nt < 2 ? xh0 : xh1)
                             : r == 1 ? (nt < 2 ? xh2 : xh3)
                             : r == 2 ? (nt < 2 ? xh4 : xh5)
                                      : (nt < 2 ? xh6 : xh7));
                float xv = (float)xp_pair[nt & 1];
                float hv = fast_tanh(dv + xv);
                int mm = 4 * kg + r;
                hh[wb + mm * 512 + (((n >> 3) ^ mm) << 3) + (n & 7)] = (__half)hv;
            }
        }
        __syncthreads();
        cur ^= 1;
    }

    // final h is in buffer 0 (512 flips). Re-read own values, dot with Wfc.
    float po[4] = {0.f, 0.f, 0.f, 0.f};
#pragma unroll
    for (int nt = 0; nt < 4; ++nt) {
        const int n = 64 * w + 16 * nt + ln;
#pragma unroll
        for (int r = 0; r < 4; ++r) {
            int mm = 4 * kg + r;
            float hv = (float)hh[mm * 512 + (((n >> 3) ^ mm) << 3) + (n & 7)];
            po[r] += hv * wfc[nt];
        }
    }
#pragma unroll
    for (int r = 0; r < 4; ++r)
        pex[(4 * kg + r) * 128 + w * 16 + ln] = po[r];
    __syncthreads();
    if (t < 16) {
        float s = 0.f;
        for (int i = 0; i < 128; ++i) s += pex[t * 128 + i];
        out[g * 16 + t] = s + bfc[0] - 0.05f;
    }
}

extern "C" void kernel_launch(void* const* d_in, const int* in_sizes, int n_in,
                              void* d_out, int out_size, void* d_ws, size_t ws_size,
                              hipStream_t stream) {
    const float* x   = (const float*)d_in[0];
    const float* Wx  = (const float*)d_in[1];
    const float* Wh  = (const float*)d_in[2];
    const float* b   = (const float*)d_in[3];
    const float* Wfc = (const float*)d_in[4];
    const float* bfc = (const float*)d_in[5];
    float* out = (float*)d_out;

    char* ws = (char*)d_ws;
    uint2* xp2 = (uint2*)ws;                            // 134,217,728 B (RNN-layout xp)
    u32* Bg    = (u32*)(ws + 134217728);                //     262,144 B
    u32* Bh    = (u32*)(ws + 134479872);                //     524,288 B

    prepack_kernel<<<384, 512, 0, stream>>>(Wx, Wh, Bg, Bh);

    const int gemm_lds = 131072;  // 64 KB A + 2x32 KB B double-buffer
    (void)hipFuncSetAttribute((const void*)xp_mfma_kernel,
                              hipFuncAttributeMaxDynamicSharedMemorySize, gemm_lds);
    xp_mfma_kernel<<<(B_ * T_) / 128, 512, gemm_lds, stream>>>(x, (const uint4*)Bg, b, xp2);

    const int rnn_lds = 40960;    // 32 KB h double-buffer + 8 KB epilogue exchange
    (void)hipFuncSetAttribute((const void*)rnn_mfma_kernel,
                              hipFuncAttributeMaxDynamicSharedMemorySize, rnn_lds);
    rnn_mfma_kernel<<<16, 512, rnn_lds, stream>>>(xp2, (const uint4*)Bh, Wfc, bfc, out);
}

// Round 10
// 2438.825 us; speedup vs baseline: 1.0133x; 1.0133x over previous
//
#include <hip/hip_runtime.h>
#include <hip/hip_fp16.h>

typedef _Float16 h2 __attribute__((ext_vector_type(2)));
typedef _Float16 half8 __attribute__((ext_vector_type(8)));
typedef float f32x4 __attribute__((ext_vector_type(4)));
typedef unsigned int u32;

#define B_ 256
#define T_ 512
#define F_ 256
#define H_ 512

// RNN: 1024-thread blocks (16 waves = 4 waves/SIMD). Wave w = k-slice [32w,32w+32).
// Per thread: 128 resident weight pairs (8 cols x 16 pairs) -> ~170 VGPR, no LDS
// weight stream, no AGPR overflow. 16 readlanes/step (vs 32). One barrier/step.
#define NREG 128
#define NCH  (NREG / 4)   /* 32 uint4 chunks */

__device__ __forceinline__ float dot2f(u32 a, u32 b, float c) {
#if __has_builtin(__builtin_amdgcn_fdot2)
    return __builtin_amdgcn_fdot2(__builtin_bit_cast(h2, a), __builtin_bit_cast(h2, b), c, false);
#else
    h2 x = __builtin_bit_cast(h2, a), y = __builtin_bit_cast(h2, b);
    return c + (float)x[0] * (float)y[0] + (float)x[1] * (float)y[1];
#endif
}

__device__ __forceinline__ u32 packh2(float a, float b) {
    h2 v; v[0] = (_Float16)a; v[1] = (_Float16)b;
    return __builtin_bit_cast(u32, v);
}

__device__ __forceinline__ u32 pk2(float a, float b) {
#if __has_builtin(__builtin_amdgcn_cvt_pkrtz)
    return __builtin_bit_cast(u32, __builtin_amdgcn_cvt_pkrtz(a, b));
#else
    return packh2(a, b);
#endif
}

__device__ __forceinline__ float fast_tanh(float x) {
    float t = fminf(fmaxf(x, -12.f), 12.f);
    float s = __expf(2.f * t);
    return 1.f - 2.f * __builtin_amdgcn_rcpf(s + 1.f);
}

// Prepack regions (flat tid over 384*512 = 196608):
//   [0, 65536)        : Bg — MFMA-fragment-ready Wx (xp GEMM B), as in R3:
//                       f = ks*32 + (l>>4)*8 + 2j, n = nt*16 + (l&15)
//   [65536, 196608)   : greg — RNN weights for 1024-thread blocks:
//                       k -> s=k&3, t=(k>>2)&1023, i4=k>>12; i=4*i4+s (0..127)
//                       q=i>>4, p=i&15, w=t>>6, l=t&63
//                       col = l + 64q, k0 = 32w + 2p
//                       value = pack(Wh[k0][col], Wh[k0+1][col])
__global__ __launch_bounds__(512) void prepack_kernel(const float* __restrict__ Wx,
                                                      const float* __restrict__ Wh,
                                                      u32* __restrict__ Bg,
                                                      u32* __restrict__ greg) {
    int id = blockIdx.x * 512 + threadIdx.x;
    if (id < 65536) {
        int j = id & 3, l = (id >> 2) & 63, nt = (id >> 8) & 31, ks = id >> 13;
        int f = ks * 32 + (l >> 4) * 8 + 2 * j;
        int n = nt * 16 + (l & 15);
        Bg[id] = packh2(Wx[f * H_ + n], Wx[(f + 1) * H_ + n]);
    } else {
        int k = id - 65536;                  // 0..131071
        int s = k & 3, t = (k >> 2) & 1023, i4 = k >> 12;
        int i = 4 * i4 + s;
        int q = i >> 4, p = i & 15;
        int w = t >> 6, l = t & 63;
        int col = l + 64 * q;
        int k0 = 32 * w + 2 * p;
        greg[k] = packh2(Wh[k0 * H_ + col], Wh[(k0 + 1) * H_ + col]);
    }
}

__device__ __forceinline__ void gload16(const uint4* g, uint4* l) {
    __builtin_amdgcn_global_load_lds((const __attribute__((address_space(1))) u32*)g,
                                     (__attribute__((address_space(3))) u32*)l, 16, 0, 0);
}

// MFMA GEMM (R3-verified): xp[row][n] = f16( sum_f x[row][f]*Wx[f][n] + b[n] )
__global__ __launch_bounds__(512) void xp_mfma_kernel(const float* __restrict__ x,
                                                      const uint4* __restrict__ Bg,
                                                      const float* __restrict__ b,
                                                      __half* __restrict__ xp) {
    extern __shared__ u32 smem[];
    uint4* alds  = (uint4*)smem;      // 4096 uint4 = 64 KB
    uint4* bbuf0 = alds + 4096;       // 2048 uint4 = 32 KB
    uint4* bbuf1 = bbuf0 + 2048;      // 2048 uint4 = 32 KB

    const int tid  = threadIdx.x;
    const int lane = tid & 63;
    const int w    = tid >> 6;
    const int cg   = w & 1;
    const int rg   = w >> 1;
    const long row0 = (long)blockIdx.x * 128;

#pragma unroll
    for (int it = 0; it < 4; ++it)
        gload16(Bg + it * 512 + tid, bbuf0 + it * 512 + tid);

    const float4* x4 = (const float4*)(x + row0 * F_);
#pragma unroll
    for (int it = 0; it < 8; ++it) {
        int s  = it * 512 + tid;
        int rt = s >> 9, ks = (s >> 6) & 7, l = s & 63;
        int row = rt * 16 + (l & 15);
        int f0  = ks * 32 + (l >> 4) * 8;
        float4 a = x4[row * 64 + (f0 >> 2)];
        float4 c = x4[row * 64 + (f0 >> 2) + 1];
        uint4 pv;
        pv.x = packh2(a.x, a.y); pv.y = packh2(a.z, a.w);
        pv.z = packh2(c.x, c.y); pv.w = packh2(c.z, c.w);
        alds[s] = pv;
    }

    float bias[16];
#pragma unroll
    for (int nt = 0; nt < 16; ++nt) bias[nt] = b[cg * 256 + nt * 16 + (lane & 15)];

    f32x4 acc0[16], acc1[16];
#pragma unroll
    for (int nt = 0; nt < 16; ++nt) {
        acc0[nt] = (f32x4){0.f, 0.f, 0.f, 0.f};
        acc1[nt] = (f32x4){0.f, 0.f, 0.f, 0.f};
    }

    __syncthreads();

#pragma unroll
    for (int ks = 0; ks < 8; ++ks) {
        const uint4* blr = (ks & 1) ? bbuf1 : bbuf0;
        if (ks < 7) {
            uint4* bw = (ks & 1) ? bbuf0 : bbuf1;
            const uint4* gs = Bg + (ks + 1) * 2048;
#pragma unroll
            for (int it = 0; it < 4; ++it)
                gload16(gs + it * 512 + tid, bw + it * 512 + tid);
        }
        uint4 af0 = alds[((rg * 2 + 0) * 8 + ks) * 64 + lane];
        uint4 af1 = alds[((rg * 2 + 1) * 8 + ks) * 64 + lane];
        half8 a0 = __builtin_bit_cast(half8, af0);
        half8 a1 = __builtin_bit_cast(half8, af1);
#pragma unroll
        for (int nt = 0; nt < 16; ++nt) {
            uint4 bf = blr[(cg * 16 + nt) * 64 + lane];
            half8 bb = __builtin_bit_cast(half8, bf);
            acc0[nt] = __builtin_amdgcn_mfma_f32_16x16x32_f16(a0, bb, acc0[nt], 0, 0, 0);
            acc1[nt] = __builtin_amdgcn_mfma_f32_16x16x32_f16(a1, bb, acc1[nt], 0, 0, 0);
        }
        __syncthreads();
    }

    const int m0 = (lane >> 4) * 4;
    const int cn = cg * 256 + (lane & 15);
#pragma unroll
    for (int mt = 0; mt < 2; ++mt) {
        long rbase = row0 + (rg * 2 + mt) * 16 + m0;
        const f32x4* accp = mt ? acc1 : acc0;
#pragma unroll
        for (int nt = 0; nt < 16; ++nt) {
            f32x4 v = accp[nt];
            int col = cn + nt * 16;
#pragma unroll
            for (int r = 0; r < 4; ++r)
                xp[(rbase + r) * H_ + col] = __float2half(v[r] + bias[nt]);
        }
    }
}

// Wave-k-slice RNN, 1024 threads (16 waves, 4/SIMD). Wave w: pairs [16w, 16w+16).
// Thread (w,l): partials for columns l+64q, q in [0,8). Tanh columns 64*(w>>1)+l
// computed redundantly by wave pairs (2j,2j+1) so readlane stays intra-wave.
__global__ __launch_bounds__(1024) __attribute__((amdgpu_waves_per_eu(4, 4)))
void rnn_kernel(const __half* __restrict__ xp,
                const u32* __restrict__ greg,
                const float* __restrict__ Wfc,
                const float* __restrict__ bfc,
                float* __restrict__ out) {
    extern __shared__ u32 lds[];
    float* part = (float*)lds;            // 2 x 16*512 f32 = 65536 B
    const int t = threadIdx.x;
    const int w = t >> 6;
    const int l = t & 63;
    const int o = w & 1;
    const int j = w >> 1;
    const int b = blockIdx.x;
    const int cc = 64 * j + l;            // tanh column owned (redundantly) by this thread

    u32 wregs[NREG];                      // wregs[q*16+p]
    const uint4* greg4 = (const uint4*)greg;
#pragma unroll
    for (int i4 = 0; i4 < NCH; ++i4) {
        uint4 v = greg4[i4 * 1024 + t];
        wregs[4 * i4 + 0] = v.x; wregs[4 * i4 + 1] = v.y;
        wregs[4 * i4 + 2] = v.z; wregs[4 * i4 + 3] = v.w;
    }

    const __half* xprow = xp + (size_t)b * T_ * H_ + cc;
    float xpv = __half2float(xprow[0]);
    int hp[16];
#pragma unroll
    for (int p = 0; p < 16; ++p) hp[p] = 0;  // h0 = 0
    __syncthreads();

    float hn = 0.f;
    int buf = 0;
    for (int ts = 0; ts < T_; ++ts) {
        int tn = (ts + 1 < T_) ? (ts + 1) : ts;
        __half nxt = xprow[(size_t)tn * H_];   // independent global prefetch
        float acc[8];
#pragma unroll
        for (int q = 0; q < 8; ++q) acc[q] = 0.f;
#pragma unroll
        for (int p = 0; p < 16; ++p) {
#pragma unroll
            for (int q = 0; q < 8; ++q)
                acc[q] = dot2f((u32)hp[p], wregs[q * 16 + p], acc[q]);
        }
        float* pb = part + buf * 8192;
#pragma unroll
        for (int q = 0; q < 8; ++q) pb[w * 512 + l + 64 * q] = acc[q];  // 2 lanes/bank = free
        __syncthreads();
        // sum 16 wave-partials for column cc (conflict-free b32, broadcast across wave pair)
        const float* pr = pb + cc;
        float r0 = pr[0 * 512] + pr[1 * 512],   r1 = pr[2 * 512] + pr[3 * 512];
        float r2 = pr[4 * 512] + pr[5 * 512],   r3 = pr[6 * 512] + pr[7 * 512];
        float r4 = pr[8 * 512] + pr[9 * 512],   r5 = pr[10 * 512] + pr[11 * 512];
        float r6 = pr[12 * 512] + pr[13 * 512], r7 = pr[14 * 512] + pr[15 * 512];
        float s = (xpv + ((r0 + r1) + (r2 + r3))) + ((r4 + r5) + (r6 + r7));
        hn = fast_tanh(s);
        xpv = __half2float(nxt);
        // redistribute: even lane e holds pack(h[64j+e], h[64j+e+1]);
        // wave w needs pairs k0 = 32w+2p -> own lane 32o+2p.
        float nb = __shfl_xor(hn, 1, 64);
        u32 pair = pk2(hn, nb);
#pragma unroll
        for (int p = 0; p < 16; ++p)
            hp[p] = __builtin_amdgcn_readlane((int)pair, 32 * o + 2 * p);
        buf ^= 1;
    }

    // epilogue: out[b] = h_last . Wfc + bfc - 0.05; even waves contribute (each col once)
    __syncthreads();
    float* red = part;
    if (o == 0) {
        float v = hn * Wfc[cc];
#pragma unroll
        for (int off = 32; off; off >>= 1) v += __shfl_down(v, off, 64);
        if (l == 0) red[j] = v;
    }
    __syncthreads();
    if (t == 0) {
        float ssum = 0.f;
        for (int jj = 0; jj < 8; ++jj) ssum += red[jj];
        out[b] = ssum + bfc[0] - 0.05f;
    }
}

extern "C" void kernel_launch(void* const* d_in, const int* in_sizes, int n_in,
                              void* d_out, int out_size, void* d_ws, size_t ws_size,
                              hipStream_t stream) {
    const float* x   = (const float*)d_in[0];
    const float* Wx  = (const float*)d_in[1];
    const float* Wh  = (const float*)d_in[2];
    const float* b   = (const float*)d_in[3];
    const float* Wfc = (const float*)d_in[4];
    const float* bfc = (const float*)d_in[5];
    float* out = (float*)d_out;

    char* ws = (char*)d_ws;
    __half* xp  = (__half*)ws;                          // 134,217,728 B
    u32* Bg     = (u32*)(ws + 134217728);               //     262,144 B
    u32* greg   = (u32*)(ws + 134479872);               //     524,288 B

    prepack_kernel<<<384, 512, 0, stream>>>(Wx, Wh, Bg, greg);

    const int gemm_lds = 131072;  // 64 KB A + 2x32 KB B double-buffer
    (void)hipFuncSetAttribute((const void*)xp_mfma_kernel,
                              hipFuncAttributeMaxDynamicSharedMemorySize, gemm_lds);
    xp_mfma_kernel<<<(B_ * T_) / 128, 512, gemm_lds, stream>>>(x, (const uint4*)Bg, b, xp);

    const int rnn_lds = 2 * 16 * 512 * 4;  // 65536 B double-buffered partials
    (void)hipFuncSetAttribute((const void*)rnn_kernel,
                              hipFuncAttributeMaxDynamicSharedMemorySize, rnn_lds);
    rnn_kernel<<<B_, 1024, rnn_lds, stream>>>(xp, greg, Wfc, bfc, out);
}